// Round 16
// baseline (93.720 us; speedup 1.0000x reference)
//
#include <hip/hip_runtime.h>

#define VOCAB 4096
#define SLICES 16
#define SLICE 256            // codes per slice (16-way split per point-set)
#define GRP 8                // codes per max-tree group
#define NGRP (SLICE / GRP)   // 32 groups per slice
#define P 4                  // points per lane
#define PTS (64 * P)         // 256 points per block
#define THREADS 1024

typedef float v2f __attribute__((ext_vector_type(2)));

// Empty-asm register barrier: forces the value into a VGPR, preventing
// fma-contraction / reassociation across it. Emits no instruction.
__device__ __forceinline__ float opaque(float x) {
  asm volatile("" : "+v"(x));
  return x;
}

// v_pk_fma_f32: per-half IEEE f32 fma — bit-identical to two scalar fmaf
// (validated R4: absmax 0.0 with this exact asm pattern). One issue slot
// for two lanes-worth of fma.
__device__ __forceinline__ v2f pk_fma(v2f a, v2f b, v2f c) {
  v2f d;
  asm("v_pk_fma_f32 %0, %1, %2, %3" : "=v"(d) : "v"(a), "v"(b), "v"(c));
  return d;
}

// v_max3_f32 / v_med3_f32: exact (no rounding) for finite inputs.
__device__ __forceinline__ float max3f(float a, float b, float c) {
  float d;
  asm("v_max3_f32 %0, %1, %2, %3" : "=v"(d) : "v"(a), "v"(b), "v"(c));
  return d;
}
__device__ __forceinline__ float med3f(float a, float b, float c) {
  float d;
  asm("v_med3_f32 %0, %1, %2, %3" : "=v"(d) : "v"(a), "v"(b), "v"(c));
  return d;
}

// Prep: pair-record packing. Group g holds codes [8g, 8g+7]; pair i of
// group g couples codes a=8g+i and b=8g+i+4. Records (float4):
//   cw[8g+2i]   = {e0[a], e0[b], e1[a], e1[b]}
//   cw[8g+2i+1] = {e2[a], e2[b], h[a],  h[b]}
// h = -0.5f*c, c = ((e0*e0+e1*e1)+e2*e2) rounded exactly like numpy
// (opaque barriers). h is an exact scale of c. Also zeroes the loss slot.
__global__ __launch_bounds__(256) void vq_prep_kernel(
    const float* __restrict__ cb, float4* __restrict__ cw,
    float* __restrict__ loss_slot) {
  int r = blockIdx.x * 256 + threadIdx.x;      // pair id, 0..2047
  if (r == 0) *loss_slot = 0.0f;
  if (r >= VOCAB / 2) return;
  int g = r >> 2, i = r & 3;
  int a = g * 8 + i, b = a + 4;
  float a0 = cb[3 * a + 0], a1 = cb[3 * a + 1], a2 = cb[3 * a + 2];
  float b0 = cb[3 * b + 0], b1 = cb[3 * b + 1], b2 = cb[3 * b + 2];
  float pa0 = opaque(a0 * a0), pa1 = opaque(a1 * a1), pa2 = opaque(a2 * a2);
  float ha = -0.5f * opaque(opaque(pa0 + pa1) + pa2);
  float pb0 = opaque(b0 * b0), pb1 = opaque(b1 * b1), pb2 = opaque(b2 * b2);
  float hb = -0.5f * opaque(opaque(pb0 + pb1) + pb2);
  cw[(size_t)(g * 8 + 2 * i)] = make_float4(a0, b0, a1, b1);
  cw[(size_t)(g * 8 + 2 * i + 1)] = make_float4(a2, b2, ha, hb);
}

// Bit-exact numpy f32 distance (validated absmax=0.0 R10-R15), scalar form:
//   m = x.e (fma ascending k, first term single-rounded mul)
//   d = (a - 2m) + c;  c = -2*h exact (fma-contract-safe).
__device__ __forceinline__ float dist_f32s(float x0, float x1, float x2,
                                           float a, float e0, float e1,
                                           float e2, float h) {
  float m = fmaf(x2, e2, fmaf(x1, e1, x0 * e0));
  return fmaf(-2.0f, m, a) + (-2.0f * h);
}

// Main: 256 blocks x 1024 threads; block = 256 points (4/lane) x 16 slices.
// Pair-record codebook staged in LDS; pk-fma surrogate scan; margin-
// certified 8-code exact rescan; bounded cooperative bit-exact fallback.
__global__ __launch_bounds__(THREADS) void vq_kernel(
    const float* __restrict__ feats, const float4* __restrict__ cw,
    float* __restrict__ out_quant, float* __restrict__ out_idx,
    float* __restrict__ out_loss, int npts) {
  __shared__ float4 sTab[VOCAB];            // 64 KB pair-record codebook
  __shared__ float sT1[SLICES * PTS];       // 16 KB per-slice best t
  __shared__ float sT2[SLICES * PTS];       // 16 KB per-slice 2nd-best
  __shared__ int sG[SLICES * PTS];          // 16 KB per-slice group base
  __shared__ unsigned long long sSlot[PTS]; // 2 KB fallback (d,idx) keys
  __shared__ int sList[PTS];                // 1 KB flagged point ids
  __shared__ int sCount;
  __shared__ double sL[PTS];                // 2 KB loss partials

  const int tid = threadIdx.x;
  const int lane = tid & 63;
  const int s = tid >> 6;                   // slice id 0..15 (wave-uniform)

  if (tid == 0) sCount = 0;

  // Stage codebook: coalesced float4 copy, 4 per thread (R14's fast path).
#pragma unroll
  for (int k = 0; k < VOCAB / THREADS; ++k)
    sTab[tid + k * THREADS] = cw[tid + k * THREADS];

  const int pbase = blockIdx.x * PTS;
  // Lane's P points: pbase + k*64 + lane (same for all waves).
  float px[P], py[P], pz[P], nn[P];
  v2f xx0[P], xx1[P], xx2[P];
#pragma unroll
  for (int k = 0; k < P; ++k) {
    const int p = pbase + k * 64 + lane;
    px[k] = feats[3 * p + 0];
    py[k] = feats[3 * p + 1];
    pz[k] = feats[3 * p + 2];
    // ||x||^2 exactly as numpy: products rounded, then ((p0+p1)+p2)
    float q0 = opaque(px[k] * px[k]);
    float q1 = opaque(py[k] * py[k]);
    float q2 = opaque(pz[k] * pz[k]);
    nn[k] = opaque(opaque(q0 + q1) + q2);
    xx0[k] = (v2f){px[k], px[k]};
    xx1[k] = (v2f){py[k], py[k]};
    xx2[k] = (v2f){pz[k], pz[k]};
  }

  __syncthreads();  // staging complete

  const float4* cs = sTab + s * SLICE;  // float4 idx == code idx per group

  // Phase 1: pk-fma surrogate max-scan. Per pair i: t = {t[a], t[b]} with
  // t = x.e - c/2 per half, IEEE-identical to the scalar 3-fma chain.
  float t1[P], t2[P];
  int gg[P];
#pragma unroll
  for (int k = 0; k < P; ++k) { t1[k] = -3.4e38f; t2[k] = -3.4e38f; gg[k] = 0; }
#pragma unroll 2
  for (int g = 0; g < NGRP; ++g) {
    const float4* gp = cs + g * GRP;  // 128 B group, broadcast reads
    float4 F0 = gp[0], F1 = gp[1], F2 = gp[2], F3 = gp[3];
    float4 F4 = gp[4], F5 = gp[5], F6 = gp[6], F7 = gp[7];
#pragma unroll
    for (int k = 0; k < P; ++k) {
      // pair i: c0=F(2i).xy, c1=F(2i).zw, c2=F(2i+1).xy, h=F(2i+1).zw
      v2f u0 = pk_fma(xx0[k], (v2f){F0.x, F0.y},
               pk_fma(xx1[k], (v2f){F0.z, F0.w},
               pk_fma(xx2[k], (v2f){F1.x, F1.y}, (v2f){F1.z, F1.w})));
      v2f u1 = pk_fma(xx0[k], (v2f){F2.x, F2.y},
               pk_fma(xx1[k], (v2f){F2.z, F2.w},
               pk_fma(xx2[k], (v2f){F3.x, F3.y}, (v2f){F3.z, F3.w})));
      v2f u2 = pk_fma(xx0[k], (v2f){F4.x, F4.y},
               pk_fma(xx1[k], (v2f){F4.z, F4.w},
               pk_fma(xx2[k], (v2f){F5.x, F5.y}, (v2f){F5.z, F5.w})));
      v2f u3 = pk_fma(xx0[k], (v2f){F6.x, F6.y},
               pk_fma(xx1[k], (v2f){F6.z, F6.w},
               pk_fma(xx2[k], (v2f){F7.x, F7.y}, (v2f){F7.z, F7.w})));
      // 8-way max over the scalar halves (tree shape irrelevant: max exact,
      // group-level tie-break only).
      float gm = max3f(max3f(u0.x, u0.y, u1.x), max3f(u1.y, u2.x, u2.y),
                       fmaxf(u3.x, u3.y));
      t2[k] = med3f(t2[k], t1[k], gm);         // streaming top-2 (1 inst)
      if (gm > t1[k]) gg[k] = g;               // strict >: earliest group
      t1[k] = fmaxf(t1[k], gm);
    }
  }
#pragma unroll
  for (int k = 0; k < P; ++k) {
    sT1[s * PTS + k * 64 + lane] = t1[k];
    sT2[s * PTS + k * 64 + lane] = t2[k];
    sG[s * PTS + k * 64 + lane] = s * SLICE + gg[k] * GRP;  // code base
  }
  __syncthreads();

  // Epilogue combine: tid < 256 owns block-point pt == tid; coords are its
  // own registers' point k == s (waves 0..3 cover tid 0..255).
  int bi = 0;
  float q0 = 0.0f, q1 = 0.0f, q2 = 0.0f;
  bool flagged = false;
  float x0 = px[0], x1 = py[0], x2 = pz[0], a = nn[0];
#pragma unroll
  for (int k = 1; k < P; ++k) {
    if (s == k) { x0 = px[k]; x1 = py[k]; x2 = pz[k]; a = nn[k]; }
  }
  if (tid < PTS) {
    float b1 = sT1[tid], b2 = sT2[tid];
    int gbase = sG[tid];
#pragma unroll
    for (int k = 1; k < SLICES; ++k) {  // ascending slice order
      float u1 = sT1[k * PTS + tid];
      float u2 = sT2[k * PTS + tid];
      b2 = fmaxf(fmaxf(b2, u2), fminf(b1, u1));
      if (u1 > b1) gbase = sG[k * PTS + tid];
      b1 = fmaxf(b1, u1);
    }
    // Margin test (validated R10/R12-R15): eps = a*2^-21 + 2^-20 (2x safe).
    float eps = fmaf(a, 0x1p-21f, 0x1p-20f);
    flagged = !((b1 - b2) > eps);
    if (flagged) {
      int pos = atomicAdd(&sCount, 1);
      sList[pos] = tid;
      sSlot[tid] = ~0ULL;
    } else {
      // Bit-exact rescan of the certified 8-code group, unpacking the pair
      // records; ascending code order, strict <: np.argmin first-occurrence.
      float bd = 3.4e38f;
#pragma unroll
      for (int k = 0; k < GRP; ++k) {
        int i = k & 3;
        bool hi = k >= 4;
        float4 A = sTab[gbase + 2 * i];
        float4 B = sTab[gbase + 2 * i + 1];
        float e0 = hi ? A.y : A.x, e1 = hi ? A.w : A.z;
        float e2 = hi ? B.y : B.x, h = hi ? B.w : B.z;
        float d = dist_f32s(x0, x1, x2, a, e0, e1, e2, h);
        if (d < bd) { bd = d; bi = gbase + k; q0 = e0; q1 = e1; q2 = e2; }
      }
    }
  }
  __syncthreads();

  // Phase 2: cooperative bit-exact full rescan for flagged points.
  // 1024 threads x 4 codes each; sortable (d,idx) key min-reduce.
  const int cnt = sCount;
  for (int f = 0; f < cnt; ++f) {
    const int fpt = sList[f];
    const int fp = pbase + fpt;
    float y0 = feats[3 * fp + 0];   // same addr all threads -> broadcast
    float y1 = feats[3 * fp + 1];
    float y2 = feats[3 * fp + 2];
    float yp0 = opaque(y0 * y0);
    float yp1 = opaque(y1 * y1);
    float yp2 = opaque(y2 * y2);
    float ay = opaque(opaque(yp0 + yp1) + yp2);
    float bd = 3.4e38f;
    int bj = 0;
#pragma unroll
    for (int k = 0; k < VOCAB / THREADS; ++k) {
      int j = tid * (VOCAB / THREADS) + k;     // ascending within thread
      int g8 = (j >> 3) << 3, i = j & 3;
      bool hi = (j & 4) != 0;
      float4 A = sTab[g8 + 2 * i];
      float4 B = sTab[g8 + 2 * i + 1];
      float e0 = hi ? A.y : A.x, e1 = hi ? A.w : A.z;
      float e2 = hi ? B.y : B.x, h = hi ? B.w : B.z;
      float d = dist_f32s(y0, y1, y2, ay, e0, e1, e2, h);
      if (d < bd) { bd = d; bj = j; }
    }
    unsigned b = __float_as_uint(bd);
    b = (b & 0x80000000u) ? ~b : (b | 0x80000000u);  // total-order transform
    unsigned long long key = ((unsigned long long)b << 32) | (unsigned)bj;
#pragma unroll
    for (int off = 1; off < 64; off <<= 1) {         // wave min-butterfly
      unsigned long long o = __shfl_xor(key, off);
      key = (o < key) ? o : key;
    }
    if (lane == 0) atomicMin(&sSlot[fpt], key);      // 16 atomics/point
  }
  __syncthreads();

  if (tid < PTS) {
    if (flagged) {
      bi = (int)(unsigned)(sSlot[tid] & 0xFFFFFFFFu);
      int g8 = (bi >> 3) << 3, i = bi & 3;
      bool hi = (bi & 4) != 0;
      float4 A = sTab[g8 + 2 * i];
      float4 B = sTab[g8 + 2 * i + 1];
      q0 = hi ? A.y : A.x; q1 = hi ? A.w : A.z; q2 = hi ? B.y : B.x;
    }
    const int p = pbase + tid;
    // straight-through: t = q - x (f32), out = x + t (f32), like reference
    float t0 = q0 - x0, t1d = q1 - x1, t2d = q2 - x2;
    out_quant[3 * p + 0] = x0 + t0;
    out_quant[3 * p + 1] = x1 + t1d;
    out_quant[3 * p + 2] = x2 + t2d;
    out_idx[p] = (float)bi;
    sL[tid] = (double)t0 * t0 + (double)t1d * t1d + (double)t2d * t2d;
  }
  __syncthreads();

  if (tid == 0) {
    double acc = 0.0;
#pragma unroll 8
    for (int k = 0; k < PTS; ++k) acc += sL[k];
    // loss = mean((q-x)^2) + 0.25*mean((x-q)^2) = 1.25 * sum / (npts*3)
    atomicAdd(out_loss, (float)(acc * (1.25 / ((double)npts * 3.0))));
  }
}

extern "C" void kernel_launch(void* const* d_in, const int* in_sizes, int n_in,
                              void* d_out, int out_size, void* d_ws,
                              size_t ws_size, hipStream_t stream) {
  const float* feats = (const float*)d_in[0];      // (B*L, 3) f32
  const float* cb = (const float*)d_in[1];         // (4096, 3) f32
  const int npts = in_sizes[0] / 3;                // 65536

  float* out = (float*)d_out;
  float* out_quant = out;                          // npts*3 elems
  float* out_idx = out + in_sizes[0];              // npts elems
  float* out_loss = out + in_sizes[0] + npts;      // 1 elem

  float4* cw = (float4*)d_ws;                      // 4096 * 16 B = 64 KB

  vq_prep_kernel<<<(VOCAB / 2 + 255) / 256, 256, 0, stream>>>(cb, cw,
                                                              out_loss);
  vq_kernel<<<npts / PTS, THREADS, 0, stream>>>(feats, cw, out_quant, out_idx,
                                                out_loss, npts);
}

// Round 17
// 88.784 us; speedup vs baseline: 1.0556x; 1.0556x over previous
//
#include <hip/hip_runtime.h>

#define VOCAB 4096
#define SLICES 16
#define SLICE 256            // codes per slice (one slice per wave)
#define HALFSLICE 128        // codes per half-wave
#define GRP 8                // codes per max-tree group
#define NGRPH (HALFSLICE / GRP)  // 16 groups per half
#define P 8                  // points per lane (each point in 2 lanes)
#define PTS 256              // points per block
#define THREADS 1024

// Empty-asm register barrier: forces the value into a VGPR, preventing
// fma-contraction / reassociation across it. Emits no instruction.
__device__ __forceinline__ float opaque(float x) {
  asm volatile("" : "+v"(x));
  return x;
}

// v_max3_f32 / v_med3_f32: exact (no rounding) for finite inputs.
__device__ __forceinline__ float max3f(float a, float b, float c) {
  float d;
  asm("v_max3_f32 %0, %1, %2, %3" : "=v"(d) : "v"(a), "v"(b), "v"(c));
  return d;
}
__device__ __forceinline__ float med3f(float a, float b, float c) {
  float d;
  asm("v_med3_f32 %0, %1, %2, %3" : "=v"(d) : "v"(a), "v"(b), "v"(c));
  return d;
}

// Prep (R14's validated layout): per-code {e0, e1, e2, h}, h = -0.5f*c,
// c = ((e0*e0+e1*e1)+e2*e2) rounded exactly like numpy (opaque barriers).
// h is an exact scale of c. Also zeroes the loss slot.
__global__ __launch_bounds__(256) void vq_prep_kernel(
    const float* __restrict__ cb, float4* __restrict__ cw,
    float* __restrict__ loss_slot) {
  int j = blockIdx.x * 256 + threadIdx.x;
  if (j == 0) *loss_slot = 0.0f;
  if (j < VOCAB) {
    float e0 = cb[3 * j + 0];
    float e1 = cb[3 * j + 1];
    float e2 = cb[3 * j + 2];
    float p0 = opaque(e0 * e0);
    float p1 = opaque(e1 * e1);
    float p2 = opaque(e2 * e2);
    float c = opaque(opaque(p0 + p1) + p2);
    cw[j] = make_float4(e0, e1, e2, -0.5f * c);
  }
}

// Surrogate scan value: t = x.e - c/2 (3 fma). Exact relation: a - 2T = D.
__device__ __forceinline__ float tval(float x0, float x1, float x2,
                                      float4 cd) {
  return fmaf(x0, cd.x, fmaf(x1, cd.y, fmaf(x2, cd.z, cd.w)));
}

// Bit-exact numpy f32 distance (validated absmax=0.0 R10-R16):
//   m = x.e (fma ascending k, first term single-rounded mul)
//   d = (a - 2m) + c;  c = -2*h exact (fma-contract-safe).
__device__ __forceinline__ float dist_f32(float x0, float x1, float x2,
                                          float a, float4 cd) {
  float m = fmaf(x2, cd.z, fmaf(x1, cd.y, x0 * cd.x));
  return fmaf(-2.0f, m, a) + (-2.0f * cd.w);
}

// Main: 256 blocks x 1024 threads; block = 256 points x 16 slices.
// Half-wave code split: lanes 0-31 stream codes [0,128) of the wave's
// slice, lanes 32-63 stream [128,256) — ONE ds_read_b128 serves 2 codes
// (2 distinct addrs per wave = conflict-free). Each point lives in lanes
// l and l^32 (P=8: point = k*32 + (lane&31)); halves merge via shfl_xor.
__global__ __launch_bounds__(THREADS) void vq_kernel(
    const float* __restrict__ feats, const float4* __restrict__ cw,
    float* __restrict__ out_quant, float* __restrict__ out_idx,
    float* __restrict__ out_loss, int npts) {
  __shared__ float4 sTab[VOCAB];            // 64 KB staged codebook
  __shared__ float sT1[SLICES * PTS];       // 16 KB per-slice best t
  __shared__ float sT2[SLICES * PTS];       // 16 KB per-slice 2nd-best
  __shared__ int sG[SLICES * PTS];          // 16 KB per-slice group base
  __shared__ unsigned long long sSlot[PTS]; // 2 KB fallback (d,idx) keys
  __shared__ int sList[PTS];                // 1 KB flagged point ids
  __shared__ int sCount;
  __shared__ double sL[PTS];                // 2 KB loss partials

  const int tid = threadIdx.x;
  const int lane = tid & 63;
  const int s = tid >> 6;                   // slice id 0..15 (wave-uniform)
  const int m = lane & 31;                  // point sub-index 0..31
  const int half = lane >> 5;               // code half 0/1

  if (tid == 0) sCount = 0;

  // Stage codebook: coalesced float4 copy, 4 per thread.
#pragma unroll
  for (int k = 0; k < VOCAB / THREADS; ++k)
    sTab[tid + k * THREADS] = cw[tid + k * THREADS];

  const int pbase = blockIdx.x * PTS;
  // Lane's P points: pbase + k*32 + m (lanes l and l^32 share points).
  float px[P], py[P], pz[P], nn[P];
#pragma unroll
  for (int k = 0; k < P; ++k) {
    const int p = pbase + k * 32 + m;
    px[k] = feats[3 * p + 0];
    py[k] = feats[3 * p + 1];
    pz[k] = feats[3 * p + 2];
    // ||x||^2 exactly as numpy: products rounded, then ((p0+p1)+p2)
    float q0 = opaque(px[k] * px[k]);
    float q1 = opaque(py[k] * py[k]);
    float q2 = opaque(pz[k] * pz[k]);
    nn[k] = opaque(opaque(q0 + q1) + q2);
  }

  __syncthreads();  // staging complete

  // This half-lane's code window: 128 codes starting at cbase.
  const int cbase = s * SLICE + half * HALFSLICE;
  const float4* ch = sTab + cbase;

  // Phase 1: surrogate max-scan over this half's 16 groups of 8 codes.
  float t1[P], t2[P];
  int gg[P];
#pragma unroll
  for (int k = 0; k < P; ++k) { t1[k] = -3.4e38f; t2[k] = -3.4e38f; gg[k] = 0; }
#pragma unroll 2
  for (int g = 0; g < NGRPH; ++g) {
    const float4* gp = ch + g * GRP;  // 2 addrs per wave (one per half)
    float4 c0 = gp[0], c1 = gp[1], c2 = gp[2], c3 = gp[3];
    float4 c4 = gp[4], c5 = gp[5], c6 = gp[6], c7 = gp[7];
#pragma unroll
    for (int k = 0; k < P; ++k) {
      float u0 = tval(px[k], py[k], pz[k], c0);
      float u1 = tval(px[k], py[k], pz[k], c1);
      float u2 = tval(px[k], py[k], pz[k], c2);
      float u3 = tval(px[k], py[k], pz[k], c3);
      float u4 = tval(px[k], py[k], pz[k], c4);
      float u5 = tval(px[k], py[k], pz[k], c5);
      float u6 = tval(px[k], py[k], pz[k], c6);
      float u7 = tval(px[k], py[k], pz[k], c7);
      float gm = max3f(max3f(u0, u1, u2), max3f(u3, u4, u5), fmaxf(u6, u7));
      t2[k] = med3f(t2[k], t1[k], gm);         // streaming top-2 (1 inst)
      if (gm > t1[k]) gg[k] = g;               // strict >: earliest group
      t1[k] = fmaxf(t1[k], gm);
    }
  }
  // Merge halves per point via partner-lane exchange (lane ^ 32). Lower
  // half (codes [0,128)) is earlier: strict > on other keeps first-min
  // semantics for lanes < 32, which are the only writers.
#pragma unroll
  for (int k = 0; k < P; ++k) {
    int gb = cbase + gg[k] * GRP;              // global code base
    float o1 = __shfl_xor(t1[k], 32);
    float o2 = __shfl_xor(t2[k], 32);
    int ob = __shfl_xor(gb, 32);
    float tmin = fminf(t1[k], o1);
    float m2 = fmaxf(fmaxf(t2[k], o2), tmin);
    int mb = (o1 > t1[k]) ? ob : gb;           // valid for half==0 lanes
    float m1 = fmaxf(t1[k], o1);
    if (half == 0) {
      sT1[s * PTS + k * 32 + m] = m1;
      sT2[s * PTS + k * 32 + m] = m2;
      sG[s * PTS + k * 32 + m] = mb;
    }
  }
  __syncthreads();

  // Epilogue combine: tid < 256 owns block-point pt == tid; its coords are
  // in its own registers at k = tid>>5 (since lane&31 == tid&31).
  int bi = 0;
  float q0 = 0.0f, q1 = 0.0f, q2 = 0.0f;
  bool flagged = false;
  const int ksel = tid >> 5;
  float x0 = px[0], x1 = py[0], x2 = pz[0], a = nn[0];
#pragma unroll
  for (int k = 1; k < P; ++k) {
    if (ksel == k) { x0 = px[k]; x1 = py[k]; x2 = pz[k]; a = nn[k]; }
  }
  if (tid < PTS) {
    float b1 = sT1[tid], b2 = sT2[tid];
    int gbase = sG[tid];
#pragma unroll
    for (int k = 1; k < SLICES; ++k) {  // ascending slice order
      float u1 = sT1[k * PTS + tid];
      float u2 = sT2[k * PTS + tid];
      b2 = fmaxf(fmaxf(b2, u2), fminf(b1, u1));
      if (u1 > b1) gbase = sG[k * PTS + tid];
      b1 = fmaxf(b1, u1);
    }
    // Margin test (validated R10/R12-R16): eps = a*2^-21 + 2^-20 (2x safe).
    float eps = fmaf(a, 0x1p-21f, 0x1p-20f);
    flagged = !((b1 - b2) > eps);
    if (flagged) {
      int pos = atomicAdd(&sCount, 1);
      sList[pos] = tid;
      sSlot[tid] = ~0ULL;
    } else {
      // Bit-exact rescan of the certified 8-code group (from LDS copy);
      // ascending, strict <: np.argmin first-occurrence.
      float bd = 3.4e38f;
#pragma unroll
      for (int k = 0; k < GRP; ++k) {
        float4 cd = sTab[gbase + k];
        float d = dist_f32(x0, x1, x2, a, cd);
        if (d < bd) { bd = d; bi = gbase + k; q0 = cd.x; q1 = cd.y; q2 = cd.z; }
      }
    }
  }
  __syncthreads();

  // Phase 2: cooperative bit-exact full rescan for flagged points.
  // 1024 threads x 4 codes each; sortable (d,idx) key min-reduce: min key
  // == min d, tie -> min idx (first occurrence).
  const int cnt = sCount;
  for (int f = 0; f < cnt; ++f) {
    const int fpt = sList[f];
    const int fp = pbase + fpt;
    float y0 = feats[3 * fp + 0];   // same addr all threads -> broadcast
    float y1 = feats[3 * fp + 1];
    float y2 = feats[3 * fp + 2];
    float yp0 = opaque(y0 * y0);
    float yp1 = opaque(y1 * y1);
    float yp2 = opaque(y2 * y2);
    float ay = opaque(opaque(yp0 + yp1) + yp2);
    float bd = 3.4e38f;
    int bj = 0;
#pragma unroll
    for (int k = 0; k < VOCAB / THREADS; ++k) {
      int j = tid + k * THREADS;
      float4 cd = sTab[j];
      float d = dist_f32(y0, y1, y2, ay, cd);
      if (d < bd) { bd = d; bj = j; }
    }
    unsigned b = __float_as_uint(bd);
    b = (b & 0x80000000u) ? ~b : (b | 0x80000000u);  // total-order transform
    unsigned long long key = ((unsigned long long)b << 32) | (unsigned)bj;
#pragma unroll
    for (int off = 1; off < 64; off <<= 1) {         // wave min-butterfly
      unsigned long long o = __shfl_xor(key, off);
      key = (o < key) ? o : key;
    }
    if (lane == 0) atomicMin(&sSlot[fpt], key);      // 16 atomics/point
  }
  __syncthreads();

  if (tid < PTS) {
    if (flagged) {
      bi = (int)(unsigned)(sSlot[tid] & 0xFFFFFFFFu);
      float4 cd = sTab[bi];
      q0 = cd.x; q1 = cd.y; q2 = cd.z;
    }
    const int p = pbase + tid;
    // straight-through: t = q - x (f32), out = x + t (f32), like reference
    float t0 = q0 - x0, t1d = q1 - x1, t2d = q2 - x2;
    out_quant[3 * p + 0] = x0 + t0;
    out_quant[3 * p + 1] = x1 + t1d;
    out_quant[3 * p + 2] = x2 + t2d;
    out_idx[p] = (float)bi;
    sL[tid] = (double)t0 * t0 + (double)t1d * t1d + (double)t2d * t2d;
  }
  __syncthreads();

  if (tid == 0) {
    double acc = 0.0;
#pragma unroll 8
    for (int k = 0; k < PTS; ++k) acc += sL[k];
    // loss = mean((q-x)^2) + 0.25*mean((x-q)^2) = 1.25 * sum / (npts*3)
    atomicAdd(out_loss, (float)(acc * (1.25 / ((double)npts * 3.0))));
  }
}

extern "C" void kernel_launch(void* const* d_in, const int* in_sizes, int n_in,
                              void* d_out, int out_size, void* d_ws,
                              size_t ws_size, hipStream_t stream) {
  const float* feats = (const float*)d_in[0];      // (B*L, 3) f32
  const float* cb = (const float*)d_in[1];         // (4096, 3) f32
  const int npts = in_sizes[0] / 3;                // 65536

  float* out = (float*)d_out;
  float* out_quant = out;                          // npts*3 elems
  float* out_idx = out + in_sizes[0];              // npts elems
  float* out_loss = out + in_sizes[0] + npts;      // 1 elem

  float4* cw = (float4*)d_ws;                      // 4096 * 16 B = 64 KB

  vq_prep_kernel<<<VOCAB / 256, 256, 0, stream>>>(cb, cw, out_loss);
  vq_kernel<<<npts / PTS, THREADS, 0, stream>>>(feats, cw, out_quant, out_idx,
                                                out_loss, npts);
}